// Round 1
// baseline (1202.569 us; speedup 1.0000x reference)
//
#include <hip/hip_runtime.h>
#include <hip/hip_bf16.h>
#include <cstdint>
#include <math.h>

#define N_EMB   65536
#define N_PROTO 2048
#define DIM     512

// 128x128 output tile, BK=64, double-buffered LDS, ONE barrier per K-step.
// Block 256 = 4 waves (2x2), wave tile 64x64 = 4x4 of mfma_f32_16x16x32_bf16
// (x2 k-slices per K-step). Single fused kernel: no workspace (round-1's
// multi-kernel pipeline diverged on replays).
#define BM 128
#define BN 128
#define BK 64
#define NT (DIM / BK)   // 8 K-steps

typedef __bf16 bf16x8 __attribute__((ext_vector_type(8)));
typedef float  f32x4  __attribute__((ext_vector_type(4)));

__device__ inline bf16x8 cvt8(float4 u, float4 v) {
    bf16x8 r;
    r[0] = (__bf16)u.x; r[1] = (__bf16)u.y; r[2] = (__bf16)u.z; r[3] = (__bf16)u.w;
    r[4] = (__bf16)v.x; r[5] = (__bf16)v.y; r[6] = (__bf16)v.z; r[7] = (__bf16)v.w;
    return r;
}
__device__ inline float dot4(float4 a) { return a.x*a.x + a.y*a.y + a.z*a.z + a.w*a.w; }

__global__ __launch_bounds__(256, 2) void fused_kernel(const float* __restrict__ E,
                                                       const float* __restrict__ Pm,
                                                       float* __restrict__ out) {
    // Double-buffered bf16 tiles, row stride 64 elems (128 B). 128B stride is a
    // 16-way bank hazard on ds_read_b128, so 16B slots are XOR-swizzled within
    // each row: slot' = slot ^ (row & 7). Reads then alias only (r, r+8) pairs
    // per bank = 2-way = free (m136). Write side uses the same involution.
    __shared__ __align__(16) __bf16 sA[2][BM * BK];   // 2 x 16 KB
    __shared__ __align__(16) __bf16 sB[2][BN * BK];   // 2 x 16 KB
    __shared__ __align__(16) float ldsXsq[BM];
    __shared__ __align__(16) float ldsPsq[BN];

    const int tid   = threadIdx.x;
    const int wave  = tid >> 6, lane = tid & 63;
    const int wm    = wave >> 1, wn = wave & 1;
    const int laneM = lane & 15, laneQ = lane >> 4;

    // T1: XCD-chunked bijective swizzle (nwg = 8192 = 8 * 1024). Each XCD gets
    // 1024 consecutive logical blocks; the 16 col-tiles sharing an E-panel run
    // back-to-back on one XCD's L2. x-fastest within the chunk.
    const int bid = blockIdx.x;
    const int lb  = (bid & 7) * ((N_EMB / BM) * (N_PROTO / BN) / 8) + (bid >> 3);
    const int rowBase = (lb >> 4) * BM;   // lb / (N_PROTO/BN)
    const int colBase = (lb & 15) * BN;   // lb % (N_PROTO/BN)

    // Staging identity: thread -> (row = tid/2, half h = tid&1) of BOTH tiles;
    // each thread loads 32 consecutive floats (128 B) per matrix per K-step.
    const int sRow = tid >> 1;
    const int h    = tid & 1;
    const float* gA = E  + (size_t)(rowBase + sRow) * DIM + h * 32;
    const float* gB = Pm + (size_t)(colBase + sRow) * DIM + h * 32;

    float4 a[8], b[8];                 // in-flight next K-tile (64 VGPR)
    float  ssqA = 0.0f, ssqB = 0.0f;   // fp32-exact row norms from staging regs
    f32x4  acc[4][4] = {};

    auto loadT = [&](int kt) {         // issue-early: 16 x global_load_dwordx4
        const float* pA = gA + kt * BK;
        const float* pB = gB + kt * BK;
        #pragma unroll
        for (int j = 0; j < 8; ++j) a[j] = *(const float4*)(pA + j * 4);
        #pragma unroll
        for (int j = 0; j < 8; ++j) b[j] = *(const float4*)(pB + j * 4);
    };
    auto stageT = [&](int dst) {       // write-late: cvt + norm + swizzled ds_write
        #pragma unroll
        for (int j = 0; j < 8; ++j) ssqA += dot4(a[j]);
        #pragma unroll
        for (int j = 0; j < 8; ++j) ssqB += dot4(b[j]);
        __bf16* wAp = &sA[dst][sRow * BK];
        __bf16* wBp = &sB[dst][sRow * BK];
        #pragma unroll
        for (int j = 0; j < 4; ++j) {
            const int sl = ((((h << 2) + j) ^ (sRow & 7)) << 3);  // 16B slot swizzle
            *(bf16x8*)(wAp + sl) = cvt8(a[2 * j], a[2 * j + 1]);
            *(bf16x8*)(wBp + sl) = cvt8(b[2 * j], b[2 * j + 1]);
        }
    };

    // Prologue: tile 0 staged into buffer 0.
    loadT(0);
    stageT(0);
    __syncthreads();

    #pragma unroll 1
    for (int kt = 0; kt < NT; ++kt) {
        const int cur = kt & 1;
        // Issue next tile's global loads; latency hides under ds_read + MFMA.
        if (kt + 1 < NT) loadT(kt + 1);

        const __bf16* rA = &sA[cur][0];
        const __bf16* rB = &sB[cur][0];
        #pragma unroll
        for (int ks = 0; ks < 2; ++ks) {
            bf16x8 af[4], bfr[4];
            #pragma unroll
            for (int mi = 0; mi < 4; ++mi)
                af[mi] = *(const bf16x8*)(rA + (wm * 64 + mi * 16 + laneM) * BK
                                             + ((((ks << 2) + laneQ) ^ (laneM & 7)) << 3));
            #pragma unroll
            for (int ni = 0; ni < 4; ++ni)
                bfr[ni] = *(const bf16x8*)(rB + (wn * 64 + ni * 16 + laneM) * BK
                                              + ((((ks << 2) + laneQ) ^ (laneM & 7)) << 3));
            #pragma unroll
            for (int mi = 0; mi < 4; ++mi)
                #pragma unroll
                for (int ni = 0; ni < 4; ++ni)
                    acc[mi][ni] = __builtin_amdgcn_mfma_f32_16x16x32_bf16(af[mi], bfr[ni], acc[mi][ni], 0, 0, 0);
        }

        // cvt + stage tile kt+1 into the OTHER buffer (no race with readers of
        // buf[cur]); the single end-of-step barrier publishes it.
        if (kt + 1 < NT) stageT(cur ^ 1);
        __syncthreads();
    }

    // Redistribute row norms: halves h=0,1 of each row combine (lanes 2r, 2r+1).
    {
        const float vA = ssqA + __shfl_xor(ssqA, 1);
        const float vB = ssqB + __shfl_xor(ssqB, 1);
        if (h == 0) { ldsXsq[sRow] = vA; ldsPsq[sRow] = vB; }
    }
    __syncthreads();

    // Epilogue: C/D layout col = lane&15, row = laneQ*4 + reg (m89-verified).
    // Nontemporal stores: output is streamed once — keep it out of L2/L3 so the
    // E panels stay resident (FETCH_SIZE was 4.2x ideal from write-thrash).
    #pragma unroll
    for (int mi = 0; mi < 4; ++mi) {
        const int rm0 = wm * 64 + mi * 16 + laneQ * 4;
        const float4 xs = *(const float4*)(ldsXsq + rm0);
        #pragma unroll
        for (int ni = 0; ni < 4; ++ni) {
            const int cn = wn * 64 + ni * 16 + laneM;
            const float pq = ldsPsq[cn];
            float* o = out + (size_t)(rowBase + rm0) * N_PROTO + (colBase + cn);
            const f32x4 c = acc[mi][ni];
            __builtin_nontemporal_store(-sqrtf(fmaxf(xs.x - 2.0f * c[0] + pq, 0.0f)), o + 0 * (size_t)N_PROTO);
            __builtin_nontemporal_store(-sqrtf(fmaxf(xs.y - 2.0f * c[1] + pq, 0.0f)), o + 1 * (size_t)N_PROTO);
            __builtin_nontemporal_store(-sqrtf(fmaxf(xs.z - 2.0f * c[2] + pq, 0.0f)), o + 2 * (size_t)N_PROTO);
            __builtin_nontemporal_store(-sqrtf(fmaxf(xs.w - 2.0f * c[3] + pq, 0.0f)), o + 3 * (size_t)N_PROTO);
        }
    }
}

extern "C" void kernel_launch(void* const* d_in, const int* in_sizes, int n_in,
                              void* d_out, int out_size, void* d_ws, size_t ws_size,
                              hipStream_t stream) {
    const float* emb = (const float*)d_in[0];
    const float* pro = (const float*)d_in[1];
    float* out = (float*)d_out;
    (void)d_ws; (void)ws_size; (void)in_sizes; (void)n_in; (void)out_size;

    fused_kernel<<<dim3((N_EMB / BM) * (N_PROTO / BN)), 256, 0, stream>>>(emb, pro, out);
}